// Round 2
// baseline (183.122 us; speedup 1.0000x reference)
//
#include <hip/hip_runtime.h>
#include <math.h>

// Fused QWZ deformation + HS-distance kernel, v4: LDS-free streaming form.
// Theory: v2 (deep ILP) == v3 (lean regs) == 54 us with VALUBusy 29%, occ 64%,
// BW 2.8 TB/s -- nothing near a roofline, so the shared two-phase LDS+barrier
// structure is the suspect. v4 removes LDS and __syncthreads entirely:
//  - each lane owns one column, walks RPT=8 rows; the (i+1) neighbor is the
//    rolling next deform, the (j+1) neighbor is a lane+1 ds_bpermute shuffle.
//  - wave covers 64 columns, outputs 63 (overlap col); +12.5% row redundancy
//    (re-deform of one boundary row per 8) instead of halo staging.
//  - 2-deep software pipeline on the 5 row loads; ~45 VGPRs, no LDS, no
//    barrier -> nothing blocks 8 waves/SIMD residency.
#define RPT   8     // output rows per thread
#define COLS  63    // output columns per wave (64 loaded, 1 overlap)
#define WAVES 4     // waves per block (stacked vertically)

struct Ld { float th, ph, ps; float2 r, im; };

__device__ __forceinline__ Ld load_row(const float* __restrict__ theta,
                                       const float* __restrict__ phi,
                                       const float* __restrict__ psi,
                                       const float2* __restrict__ sre,
                                       const float2* __restrict__ sim,
                                       int row, int col, int mesh) {
    int n = row * mesh + col;
    int an = (n > 0) ? n - 1 : 0;   // avoid theta[-1]
    Ld L;
    L.th = theta[an];
    L.ph = phi[an];
    L.ps = psi[an];
    L.r  = sre[n];
    L.im = sim[n];
    return L;
}

__device__ __forceinline__ float4 deform(Ld L, bool origin) {
    float st, ct, sp, cp, sq, cq;
    __sincosf(L.th, &st, &ct);
    __sincosf(L.ph, &sp, &cp);
    __sincosf(L.ps, &sq, &cq);
    float a = ct * cp;   // su_re diag
    float b = st * cq;   // su_re off-diag
    float c = ct * sp;   // su_im diag
    float d = st * sq;   // su_im off-diag
    // d_re = su_re@s_re - su_im@s_im ; d_im = su_re@s_im + su_im@s_re
    float4 d4;
    d4.x = a * L.r.x - b * L.r.y - c * L.im.x + d * L.im.y;
    d4.y = b * L.r.x + a * L.r.y + d * L.im.x + c * L.im.y;
    d4.z = a * L.im.x - b * L.im.y + c * L.r.x - d * L.r.y;
    d4.w = b * L.im.x + a * L.im.y - d * L.r.x - c * L.r.y;
    if (origin)          // site 0 keeps undeformed state
        d4 = make_float4(L.r.x, L.r.y, L.im.x, L.im.y);
    return d4;
}

__device__ __forceinline__ float4 shfl_dn1(float4 x) {
    float4 y;
    y.x = __shfl_down(x.x, 1, 64);
    y.y = __shfl_down(x.y, 1, 64);
    y.z = __shfl_down(x.z, 1, 64);
    y.w = __shfl_down(x.w, 1, 64);
    return y;            // lane 63 gets garbage; its stores are predicated off
}

__device__ __forceinline__ float hsdist(float4 A, float4 B) {
    float rr = A.x * B.x + A.y * B.y + A.z * B.z + A.w * B.w;
    float ri = A.x * B.z + A.y * B.w - A.z * B.x - A.w * B.y;
    return sqrtf(fabsf(1.0f - rr * rr - ri * ri));
}

__global__ __launch_bounds__(256, 8) void qwz_deform_dirichlet_kernel(
    const float* __restrict__ theta,
    const float* __restrict__ phi,
    const float* __restrict__ psi,
    const float2* __restrict__ sre,   // state_re as [N] float2
    const float2* __restrict__ sim,   // state_im as [N] float2
    float* __restrict__ out,          // [3, mesh, mesh]
    int mesh)
{
    const int N = mesh * mesh;
    const int lane = threadIdx.x & 63;
    const int wave = threadIdx.x >> 6;

    // column this lane loads & deforms (wrapped); output column is unwrapped
    const int cj = blockIdx.x * COLS + lane;
    int gj = cj;
    if (gj >= mesh) gj -= mesh;

    // first output row for this wave; rows r0..r0+RPT are deformed (last wraps)
    const int r0 = (blockIdx.y * WAVES + wave) * RPT;

    // ---- prologue: rows r0 and r0+1 in flight ----
    Ld l0 = load_row(theta, phi, psi, sre, sim, r0, gj, mesh);
    {
        int r1 = r0 + 1; if (r1 >= mesh) r1 -= mesh;
        // (r0+1 < mesh always except when RPT==1; keep the wrap for safety)
        Ld lt = load_row(theta, phi, psi, sre, sim, r1, gj, mesh);
        float4 A = deform(l0, (r0 | gj) == 0);
        float4 S = shfl_dn1(A);

        const bool do_store = (lane < COLS) && (cj < mesh);
        int site = r0 * mesh + cj;

        Ld l1 = lt;
#pragma unroll
        for (int k = 0; k < RPT; ++k) {
            Ld lc = l1;                       // data for row r0+k+1
            if (k + 2 <= RPT) {
                int rn = r0 + k + 2; if (rn >= mesh) rn -= mesh;
                l1 = load_row(theta, phi, psi, sre, sim, rn, gj, mesh);
            }
            int rw = r0 + k + 1; if (rw >= mesh) rw -= mesh;
            float4 B = deform(lc, (rw | gj) == 0);
            float4 T = shfl_dn1(B);

            float v = hsdist(A, S);           // (i,j)-(i,j+1)
            float h = hsdist(A, B);           // (i,j)-(i+1,j)
            float d = hsdist(A, T);           // (i,j)-(i+1,j+1)

            if (do_store) {
                __builtin_nontemporal_store(v, out + site);
                __builtin_nontemporal_store(h, out + N + site);
                __builtin_nontemporal_store(d, out + 2 * N + site);
            }
            A = B; S = T;
            site += mesh;
        }
    }
}

extern "C" void kernel_launch(void* const* d_in, const int* in_sizes, int n_in,
                              void* d_out, int out_size, void* d_ws, size_t ws_size,
                              hipStream_t stream) {
    const float* theta = (const float*)d_in[0];
    const float* phi   = (const float*)d_in[1];
    const float* psi   = (const float*)d_in[2];
    const float2* sre  = (const float2*)d_in[3];
    const float2* sim  = (const float2*)d_in[4];
    float* out = (float*)d_out;

    int N = in_sizes[0] + 1;                       // theta has N-1 elements
    int mesh = (int)(sqrt((double)N) + 0.5);       // 2048

    dim3 grid((mesh + COLS - 1) / COLS,            // 33 column groups
              mesh / (WAVES * RPT));               // 64 row groups
    dim3 block(256);
    qwz_deform_dirichlet_kernel<<<grid, block, 0, stream>>>(
        theta, phi, psi, sre, sim, out, mesh);
}

// Round 3
// 162.497 us; speedup vs baseline: 1.1269x; 1.1269x over previous
//
#include <hip/hip_runtime.h>
#include <math.h>

// Fused QWZ deformation + HS-distance kernel, v5: cross-tile software pipeline.
// Evidence so far: v2 (deep ILP, LDS) == v3 (lean regs, LDS) == 54us, v4
// (no-LDS streaming) == 72us; VALUBusy <=29%, BW <=46% of achievable, 0 bank
// conflicts, occupancy ~60-64% regardless of resources. Diagnosis: latency-
// bound, bursty lockstep -- each block has ONE tile, so halo-load latency is
// serially exposed before compute with nothing to overlap it.
// v5: each block walks TSTEPS=4 stacked 32x32 tiles; raw inputs for tile t+1
// are prefetched into registers BEFORE computing tile t (in flight across a
// full compute phase); deformed spinors double-buffered in LDS; ONE barrier
// per tile. 512 threads, grid 64x16=1024 blocks = exactly 4/CU, LDS 2x17.4KB.
#define TILE   32
#define HALO   33              // TILE + 1
#define NHALO  (HALO * HALO)   // 1089
#define TSTEPS 4               // tiles per block (vertical walk)
#define TPB    512
#define NBATCH 3               // ceil(NHALO / TPB)

struct Ld { float th, ph, ps; float2 r, im; };

// Issue raw-input loads for one tile's halo into registers (3 batches/thread).
__device__ __forceinline__ void load_tile(
    const float* __restrict__ theta, const float* __restrict__ phi,
    const float* __restrict__ psi, const float2* __restrict__ sre,
    const float2* __restrict__ sim,
    int bi, int bj, int mesh, int tid, Ld P[NBATCH], int nP[NBATCH])
{
#pragma unroll
    for (int b = 0; b < NBATCH; ++b) {
        int l = tid + b * TPB;
        if (l < NHALO) {
            int trow = l / HALO;
            int tcol = l - trow * HALO;
            int gi = bi + trow; if (gi >= mesh) gi -= mesh;
            int gj = bj + tcol; if (gj >= mesh) gj -= mesh;
            int n = gi * mesh + gj;
            nP[b] = n;
            int an = (n > 0) ? n - 1 : 0;   // avoid theta[-1]
            P[b].th = theta[an];
            P[b].ph = phi[an];
            P[b].ps = psi[an];
            P[b].r  = sre[n];
            P[b].im = sim[n];
        }
    }
}

// Deform the prefetched halo (trig + 2x2 complex matmul) and write to LDS.
__device__ __forceinline__ void deform_tile(
    float4* __restrict__ dst, const Ld P[NBATCH], const int nP[NBATCH], int tid)
{
#pragma unroll
    for (int b = 0; b < NBATCH; ++b) {
        int l = tid + b * TPB;
        if (l < NHALO) {
            float st, ct, sp, cp, sq, cq;
            __sincosf(P[b].th, &st, &ct);
            __sincosf(P[b].ph, &sp, &cp);
            __sincosf(P[b].ps, &sq, &cq);
            float a = ct * cp;   // su_re diag
            float bb = st * cq;  // su_re off-diag
            float c = ct * sp;   // su_im diag
            float d = st * sq;   // su_im off-diag
            float2 r = P[b].r, im = P[b].im;
            // d_re = su_re@s_re - su_im@s_im ; d_im = su_re@s_im + su_im@s_re
            float4 d4;
            d4.x = a * r.x - bb * r.y - c * im.x + d * im.y;
            d4.y = bb * r.x + a * r.y + d * im.x + c * im.y;
            d4.z = a * im.x - bb * im.y + c * r.x - d * r.y;
            d4.w = bb * im.x + a * im.y - d * r.x - c * r.y;
            if (nP[b] == 0)      // site 0 keeps undeformed state
                d4 = make_float4(r.x, r.y, im.x, im.y);
            dst[l] = d4;
        }
    }
}

__device__ __forceinline__ float hsdist(float4 A, float4 B) {
    float rr = A.x * B.x + A.y * B.y + A.z * B.z + A.w * B.w;
    float ri = A.x * B.z + A.y * B.w - A.z * B.x - A.w * B.y;
    return sqrtf(fabsf(1.0f - rr * rr - ri * ri));
}

// Compute 2 output rows/thread for one tile from LDS; nontemporal stores.
__device__ __forceinline__ void compute_tile(
    const float4* __restrict__ tl, int rt, int bj, int mesh, int N, int tid,
    float* __restrict__ out)
{
    const int trow = (tid >> 5) << 1;   // 0,2,...,30
    const int tcol = tid & 31;

    float4 A = tl[trow * HALO + tcol];
    float4 V = tl[trow * HALO + tcol + 1];
    int site = (rt + trow) * mesh + (bj + tcol);

#pragma unroll
    for (int k = 0; k < 2; ++k) {
        float4 H = tl[(trow + k + 1) * HALO + tcol];
        float4 D = tl[(trow + k + 1) * HALO + tcol + 1];

        float v = hsdist(A, V);
        float h = hsdist(A, H);
        float d = hsdist(A, D);

        __builtin_nontemporal_store(v, out + site);
        __builtin_nontemporal_store(h, out + N + site);
        __builtin_nontemporal_store(d, out + 2 * N + site);

        A = H; V = D;
        site += mesh;
    }
}

__global__ __launch_bounds__(TPB, 8) void qwz_deform_dirichlet_kernel(
    const float* __restrict__ theta,
    const float* __restrict__ phi,
    const float* __restrict__ psi,
    const float2* __restrict__ sre,
    const float2* __restrict__ sim,
    float* __restrict__ out,          // [3, mesh, mesh]
    int mesh)
{
    const int N = mesh * mesh;
    __shared__ float4 tile[2][NHALO]; // double-buffered deformed spinors

    const int bj = blockIdx.x * TILE;            // column origin
    const int r0 = blockIdx.y * (TILE * TSTEPS); // row origin of tile 0
    const int tid = threadIdx.x;

    Ld P[NBATCH]; int nP[NBATCH];

    // ---- prologue: stage tile 0, prefetch tile 1 ----
    load_tile(theta, phi, psi, sre, sim, r0, bj, mesh, tid, P, nP);
    deform_tile(tile[0], P, nP, tid);
    load_tile(theta, phi, psi, sre, sim, r0 + TILE, bj, mesh, tid, P, nP);
    __syncthreads();

#pragma unroll
    for (int t = 0; t < TSTEPS; ++t) {
        // compute tile t (reads tile[t&1]); prefetched loads for t+1 in flight
        compute_tile(tile[t & 1], r0 + t * TILE, bj, mesh, N, tid, out);

        if (t + 1 < TSTEPS) {
            // consume prefetch (vmcnt wait lands here, a full phase after issue)
            deform_tile(tile[(t + 1) & 1], P, nP, tid);
            if (t + 2 < TSTEPS)
                load_tile(theta, phi, psi, sre, sim,
                          r0 + (t + 2) * TILE, bj, mesh, tid, P, nP);
        }
        // one barrier/tile: orders {reads of tile[t&1]} before its overwrite
        // at t+2, and {writes of tile[(t+1)&1]} before reads at t+1.
        __syncthreads();
    }
}

extern "C" void kernel_launch(void* const* d_in, const int* in_sizes, int n_in,
                              void* d_out, int out_size, void* d_ws, size_t ws_size,
                              hipStream_t stream) {
    const float* theta = (const float*)d_in[0];
    const float* phi   = (const float*)d_in[1];
    const float* psi   = (const float*)d_in[2];
    const float2* sre  = (const float2*)d_in[3];
    const float2* sim  = (const float2*)d_in[4];
    float* out = (float*)d_out;

    int N = in_sizes[0] + 1;                       // theta has N-1 elements
    int mesh = (int)(sqrt((double)N) + 0.5);       // 2048

    dim3 grid(mesh / TILE, mesh / (TILE * TSTEPS)); // (64, 16) = 1024 blocks
    dim3 block(TPB);
    qwz_deform_dirichlet_kernel<<<grid, block, 0, stream>>>(
        theta, phi, psi, sre, sim, out, mesh);
}